// Round 1
// baseline (344.073 us; speedup 1.0000x reference)
//
#include <hip/hip_runtime.h>
#include <stdint.h>

#define D_MODEL 1024
#define NHEAD 16
#define DKH 64
#define BATCH 4
#define SEQ 2048
#define M_ROWS (BATCH*SEQ)   // 8192
#define NBH (BATCH*NHEAD)    // 64

typedef float f32x4 __attribute__((ext_vector_type(4)));
typedef __bf16 bf16x8 __attribute__((ext_vector_type(8)));

__device__ __forceinline__ unsigned short f2bf(float x) {
    unsigned int u = __builtin_bit_cast(unsigned int, x);
    unsigned int r = (u + 0x7FFFu + ((u >> 16) & 1u)) >> 16;   // RNE
    return (unsigned short)r;
}

#define GLL(gsrc, ldst) \
    __builtin_amdgcn_global_load_lds((const __attribute__((address_space(1))) void*)(gsrc), \
                                     (__attribute__((address_space(3))) void*)(ldst), 16, 0, 0)

// ---------------------------------------------------------------------------
// Kernel 1: fp32 -> bf16 conversion / packing
// ---------------------------------------------------------------------------
__global__ __launch_bounds__(256) void k_convert(
    const float* __restrict__ z,  const float* __restrict__ wq,
    const float* __restrict__ wk, const float* __restrict__ wv,
    const float* __restrict__ wo,
    const float* __restrict__ bq, const float* __restrict__ bk,
    const float* __restrict__ bv,
    unsigned short* __restrict__ zb, unsigned short* __restrict__ wqkv,
    unsigned short* __restrict__ wob, float* __restrict__ biasf)
{
    int i = blockIdx.x * 256 + threadIdx.x;   // 0 .. 2097151
    {
        float4 v = ((const float4*)z)[i];
        ushort4 o; o.x = f2bf(v.x); o.y = f2bf(v.y); o.z = f2bf(v.z); o.w = f2bf(v.w);
        ((ushort4*)zb)[i] = o;
    }
    if (i < 262144) {   // 1048576/4 per weight matrix
        float4 v;
        ushort4 o;
        v = ((const float4*)wq)[i];
        o.x=f2bf(v.x); o.y=f2bf(v.y); o.z=f2bf(v.z); o.w=f2bf(v.w);
        ((ushort4*)wqkv)[i] = o;
        v = ((const float4*)wk)[i];
        o.x=f2bf(v.x); o.y=f2bf(v.y); o.z=f2bf(v.z); o.w=f2bf(v.w);
        ((ushort4*)wqkv)[262144 + i] = o;
        v = ((const float4*)wv)[i];
        o.x=f2bf(v.x); o.y=f2bf(v.y); o.z=f2bf(v.z); o.w=f2bf(v.w);
        ((ushort4*)wqkv)[524288 + i] = o;
        v = ((const float4*)wo)[i];
        o.x=f2bf(v.x); o.y=f2bf(v.y); o.z=f2bf(v.z); o.w=f2bf(v.w);
        ((ushort4*)wob)[i] = o;
    }
    if (i < 1024) {
        biasf[i]        = bq[i];
        biasf[1024 + i] = bk[i];
        biasf[2048 + i] = bv[i];
    }
}

// ---------------------------------------------------------------------------
// Kernel 2: QKV projection GEMM  C[8192,3072] = zb * wqkv^T + bias
// 128x128 tile, BK=32, 4 waves, each wave 64x64 (4x4 of 16x16x32 MFMA).
// Epilogue scatters to q[b,h,s,dk], k[b,h,s,dk], vT[b,h,dk,s]  (bf16)
// ---------------------------------------------------------------------------
__global__ __launch_bounds__(256) void k_gemm_qkv(
    const unsigned short* __restrict__ A,   // [8192][1024] bf16
    const unsigned short* __restrict__ Bw,  // [3072][1024] bf16
    const float* __restrict__ biasf,        // [3072]
    unsigned short* __restrict__ qb, unsigned short* __restrict__ kb,
    unsigned short* __restrict__ vtb)
{
    __shared__ unsigned short lds_a[128 * 32];
    __shared__ unsigned short lds_b[128 * 32];

    const int NT = 3072 / 128;  // 24
    int bid = blockIdx.x;
    int tn = bid % NT, tm = bid / NT;
    int m0 = tm * 128, n0 = tn * 128;
    int tid = threadIdx.x, wid = tid >> 6, lane = tid & 63;
    int wm = wid >> 1, wn = wid & 1;

    f32x4 acc[4][4] = {};

    int srow = lane >> 2;        // 0..15
    int scol = (lane & 3) * 8;   // element offset within 32-col row

    for (int kt = 0; kt < 32; ++kt) {
        int k0 = kt * 32;
#pragma unroll
        for (int i = 0; i < 2; ++i) {
            int rb = (wid * 2 + i) * 16;
            GLL(A  + (size_t)(m0 + rb + srow) * 1024 + k0 + scol, lds_a + rb * 32);
            GLL(Bw + (size_t)(n0 + rb + srow) * 1024 + k0 + scol, lds_b + rb * 32);
        }
        __syncthreads();
        bf16x8 af[4], bfr[4];
#pragma unroll
        for (int i = 0; i < 4; ++i)
            af[i] = *(const bf16x8*)(lds_a + (wm * 64 + i * 16 + (lane & 15)) * 32 + (lane >> 4) * 8);
#pragma unroll
        for (int j = 0; j < 4; ++j)
            bfr[j] = *(const bf16x8*)(lds_b + (wn * 64 + j * 16 + (lane & 15)) * 32 + (lane >> 4) * 8);
#pragma unroll
        for (int i = 0; i < 4; ++i)
#pragma unroll
            for (int j = 0; j < 4; ++j)
                acc[i][j] = __builtin_amdgcn_mfma_f32_16x16x32_bf16(af[i], bfr[j], acc[i][j], 0, 0, 0);
        __syncthreads();
    }

    int t = n0 >> 10;  // 0=Q 1=K 2=V (uniform per block: 128 | 1024)
#pragma unroll
    for (int j = 0; j < 4; ++j) {
        int col = n0 + wn * 64 + j * 16 + (lane & 15);
        float bias = biasf[col];
        int d  = col & 1023;
        int h  = d >> 6;
        int dk = d & 63;
#pragma unroll
        for (int i = 0; i < 4; ++i) {
#pragma unroll
            for (int r = 0; r < 4; ++r) {
                int row = m0 + wm * 64 + i * 16 + (lane >> 4) * 4 + r;
                float v = acc[i][j][r] + bias;
                unsigned short bv16 = f2bf(v);
                int b_ = row >> 11, s_ = row & 2047;
                int bh = b_ * NHEAD + h;
                if (t == 0)      qb[((size_t)bh * SEQ + s_) * DKH + dk] = bv16;
                else if (t == 1) kb[((size_t)bh * SEQ + s_) * DKH + dk] = bv16;
                else             vtb[((size_t)bh * DKH + dk) * SEQ + s_] = bv16;
            }
        }
    }
}

// ---------------------------------------------------------------------------
// Kernel 3: flash attention.  1 block = one (b,h) x 64 q-rows. 4 waves x 16 rows.
// K,V tiles (64x64 bf16) staged via global_load_lds with XOR chunk swizzle
// pre-applied on the GLOBAL source (LDS dest stays linear), read back with the
// same XOR -> ~conflict-free ds_read_b128.
// ---------------------------------------------------------------------------
__global__ __launch_bounds__(256) void k_attn(
    const unsigned short* __restrict__ qb,
    const unsigned short* __restrict__ kb,
    const unsigned short* __restrict__ vtb,
    unsigned short* __restrict__ ctxb)
{
    __shared__ unsigned short lds_k[64 * 64];
    __shared__ unsigned short lds_v[64 * 64];
    __shared__ unsigned short lds_p[4][16 * 72];   // +8 pad breaks b128 row-stride conflicts

    int bid = blockIdx.x;
    int bh = bid >> 5;       // 0..63
    int qt = bid & 31;       // q tile
    int tid = threadIdx.x, wid = tid >> 6, lane = tid & 63;

    // Q fragments, held in registers for the whole block
    int qrow = qt * 64 + wid * 16 + (lane & 15);
    const unsigned short* qptr = qb + ((size_t)bh * SEQ + qrow) * DKH + (lane >> 4) * 8;
    bf16x8 aq0 = *(const bf16x8*)(qptr);
    bf16x8 aq1 = *(const bf16x8*)(qptr + 32);

    float m_run[4], l_run[4];
    f32x4 oacc[4] = {};
#pragma unroll
    for (int r = 0; r < 4; ++r) { m_run[r] = -1e30f; l_run[r] = 0.f; }

    int srow8 = lane >> 3;   // 0..7
    int sc    = lane & 7;    // 16B chunk within 128B row

    for (int kt = 0; kt < 32; ++kt) {
        // ---- stage K tile [64 kv-rows][64 d] and V^T tile [64 d][64 kv] ----
#pragma unroll
        for (int i = 0; i < 2; ++i) {
            int rb = wid * 16 + i * 8;
            int row = rb + srow8;
            int cs = (sc ^ (row & 7)) * 8;
            GLL(kb  + ((size_t)bh * SEQ + kt * 64 + row) * DKH + cs, lds_k + rb * 64);
            GLL(vtb + ((size_t)bh * DKH + row) * SEQ + kt * 64 + cs, lds_v + rb * 64);
        }
        __syncthreads();

        // ---- S = Q K^T  (16 q-rows x 64 kv-cols per wave) ----
        f32x4 sj[4] = {};
#pragma unroll
        for (int j = 0; j < 4; ++j) {
#pragma unroll
            for (int kk = 0; kk < 2; ++kk) {
                int row = j * 16 + (lane & 15);
                int cb  = kk * 4 + (lane >> 4);
                bf16x8 bk8 = *(const bf16x8*)(lds_k + row * 64 + ((cb ^ (row & 7)) * 8));
                sj[j] = __builtin_amdgcn_mfma_f32_16x16x32_bf16(kk == 0 ? aq0 : aq1, bk8, sj[j], 0, 0, 0);
            }
        }

        // ---- online softmax (scale = 1/8) ----
        float mt[4];
#pragma unroll
        for (int r = 0; r < 4; ++r)
            mt[r] = fmaxf(fmaxf(sj[0][r], sj[1][r]), fmaxf(sj[2][r], sj[3][r]));
#pragma unroll
        for (int m = 1; m < 16; m <<= 1)
#pragma unroll
            for (int r = 0; r < 4; ++r) mt[r] = fmaxf(mt[r], __shfl_xor(mt[r], m));

        float p[4][4], rs[4], alpha[4];
#pragma unroll
        for (int r = 0; r < 4; ++r) {
            float mn = fmaxf(m_run[r], mt[r] * 0.125f);
            alpha[r] = __expf(m_run[r] - mn);
            m_run[r] = mn;
            float s0 = 0.f;
#pragma unroll
            for (int j = 0; j < 4; ++j) {
                float e = __expf(sj[j][r] * 0.125f - mn);
                p[j][r] = e; s0 += e;
            }
            rs[r] = s0;
        }
#pragma unroll
        for (int m = 1; m < 16; m <<= 1)
#pragma unroll
            for (int r = 0; r < 4; ++r) rs[r] += __shfl_xor(rs[r], m);
#pragma unroll
        for (int r = 0; r < 4; ++r) l_run[r] = l_run[r] * alpha[r] + rs[r];
#pragma unroll
        for (int dj = 0; dj < 4; ++dj)
#pragma unroll
            for (int r = 0; r < 4; ++r) oacc[dj][r] *= alpha[r];

        // ---- P -> bf16 via per-wave LDS (C-layout -> A-layout repack) ----
#pragma unroll
        for (int j = 0; j < 4; ++j)
#pragma unroll
            for (int r = 0; r < 4; ++r)
                lds_p[wid][((lane >> 4) * 4 + r) * 72 + j * 16 + (lane & 15)] = f2bf(p[j][r]);
        __syncthreads();

        // ---- O += P V ----
#pragma unroll
        for (int kk = 0; kk < 2; ++kk) {
            bf16x8 pa = *(const bf16x8*)(&lds_p[wid][(lane & 15) * 72 + kk * 32 + (lane >> 4) * 8]);
#pragma unroll
            for (int dj = 0; dj < 4; ++dj) {
                int d  = dj * 16 + (lane & 15);
                int cb = kk * 4 + (lane >> 4);
                bf16x8 bv8 = *(const bf16x8*)(lds_v + d * 64 + ((cb ^ (d & 7)) * 8));
                oacc[dj] = __builtin_amdgcn_mfma_f32_16x16x32_bf16(pa, bv8, oacc[dj], 0, 0, 0);
            }
        }
        __syncthreads();
    }

    // ---- epilogue: ctx[b,s,h,dk] bf16 ----
    int b_ = bh >> 4, h = bh & 15;
#pragma unroll
    for (int r = 0; r < 4; ++r) {
        float inv = 1.0f / l_run[r];
        int s_ = qt * 64 + wid * 16 + (lane >> 4) * 4 + r;
#pragma unroll
        for (int dj = 0; dj < 4; ++dj) {
            int dk = dj * 16 + (lane & 15);
            ctxb[(((size_t)b_ * SEQ + s_) * NHEAD + h) * DKH + dk] = f2bf(oacc[dj][r] * inv);
        }
    }
}

// ---------------------------------------------------------------------------
// Kernel 4: output projection  out[8192,1024] = ctxb * wob^T + bo  (fp32 out)
// ---------------------------------------------------------------------------
__global__ __launch_bounds__(256) void k_gemm_out(
    const unsigned short* __restrict__ A,    // ctxb [8192][1024] bf16
    const unsigned short* __restrict__ Bw,   // wob  [1024][1024] bf16
    const float* __restrict__ bo,
    float* __restrict__ out)
{
    __shared__ unsigned short lds_a[128 * 32];
    __shared__ unsigned short lds_b[128 * 32];

    const int NT = 1024 / 128;  // 8
    int bid = blockIdx.x;
    int tn = bid % NT, tm = bid / NT;
    int m0 = tm * 128, n0 = tn * 128;
    int tid = threadIdx.x, wid = tid >> 6, lane = tid & 63;
    int wm = wid >> 1, wn = wid & 1;

    f32x4 acc[4][4] = {};

    int srow = lane >> 2;
    int scol = (lane & 3) * 8;

    for (int kt = 0; kt < 32; ++kt) {
        int k0 = kt * 32;
#pragma unroll
        for (int i = 0; i < 2; ++i) {
            int rb = (wid * 2 + i) * 16;
            GLL(A  + (size_t)(m0 + rb + srow) * 1024 + k0 + scol, lds_a + rb * 32);
            GLL(Bw + (size_t)(n0 + rb + srow) * 1024 + k0 + scol, lds_b + rb * 32);
        }
        __syncthreads();
        bf16x8 af[4], bfr[4];
#pragma unroll
        for (int i = 0; i < 4; ++i)
            af[i] = *(const bf16x8*)(lds_a + (wm * 64 + i * 16 + (lane & 15)) * 32 + (lane >> 4) * 8);
#pragma unroll
        for (int j = 0; j < 4; ++j)
            bfr[j] = *(const bf16x8*)(lds_b + (wn * 64 + j * 16 + (lane & 15)) * 32 + (lane >> 4) * 8);
#pragma unroll
        for (int i = 0; i < 4; ++i)
#pragma unroll
            for (int j = 0; j < 4; ++j)
                acc[i][j] = __builtin_amdgcn_mfma_f32_16x16x32_bf16(af[i], bfr[j], acc[i][j], 0, 0, 0);
        __syncthreads();
    }

#pragma unroll
    for (int j = 0; j < 4; ++j) {
        int col = n0 + wn * 64 + j * 16 + (lane & 15);
        float bias = bo[col];
#pragma unroll
        for (int i = 0; i < 4; ++i) {
#pragma unroll
            for (int r = 0; r < 4; ++r) {
                int row = m0 + wm * 64 + i * 16 + (lane >> 4) * 4 + r;
                out[(size_t)row * 1024 + col] = acc[i][j][r] + bias;
            }
        }
    }
}

// ---------------------------------------------------------------------------
extern "C" void kernel_launch(void* const* d_in, const int* in_sizes, int n_in,
                              void* d_out, int out_size, void* d_ws, size_t ws_size,
                              hipStream_t stream)
{
    const float* z  = (const float*)d_in[0];
    const float* Wq = (const float*)d_in[1];
    const float* bq = (const float*)d_in[2];
    const float* Wk = (const float*)d_in[3];
    const float* bk = (const float*)d_in[4];
    const float* Wv = (const float*)d_in[5];
    const float* bv = (const float*)d_in[6];
    const float* Wo = (const float*)d_in[7];
    const float* bo = (const float*)d_in[8];
    float* out = (float*)d_out;

    char* ws = (char*)d_ws;
    // zb region is reused as ctxb (zb dead after k_gemm_qkv)
    unsigned short* zb   = (unsigned short*)(ws);                        // 16 MB
    unsigned short* ctxb = (unsigned short*)(ws);                        // 16 MB (reuse)
    unsigned short* wqkv = (unsigned short*)(ws + (16ull << 20));        //  6 MB
    unsigned short* wob  = (unsigned short*)(ws + (22ull << 20));        //  2 MB
    float*          biasf= (float*)(ws + (24ull << 20));                 // 12 KB
    unsigned short* qb   = (unsigned short*)(ws + (25ull << 20));        // 16 MB
    unsigned short* kb   = (unsigned short*)(ws + (41ull << 20));        // 16 MB
    unsigned short* vtb  = (unsigned short*)(ws + (57ull << 20));        // 16 MB -> 73 MB total

    k_convert<<<8192, 256, 0, stream>>>(z, Wq, Wk, Wv, Wo, bq, bk, bv, zb, wqkv, wob, biasf);
    k_gemm_qkv<<<64 * 24, 256, 0, stream>>>(zb, wqkv, biasf, qb, kb, vtb);
    k_attn<<<NBH * 32, 256, 0, stream>>>(qb, kb, vtb, ctxb);
    k_gemm_out<<<64 * 8, 256, 0, stream>>>(ctxb, wob, bo, out);
}

// Round 2
// 256.873 us; speedup vs baseline: 1.3395x; 1.3395x over previous
//
#include <hip/hip_runtime.h>
#include <stdint.h>

#define D_MODEL 1024
#define NHEAD 16
#define DKH 64
#define BATCH 4
#define SEQ 2048
#define M_ROWS (BATCH*SEQ)   // 8192
#define NBH (BATCH*NHEAD)    // 64

typedef float f32x4 __attribute__((ext_vector_type(4)));
typedef __bf16 bf16x8 __attribute__((ext_vector_type(8)));
typedef __bf16 bf16x4v __attribute__((ext_vector_type(4)));
typedef short short4v __attribute__((ext_vector_type(4)));

__device__ __forceinline__ unsigned short f2bf(float x) {
    __bf16 b = (__bf16)x;                      // hardware v_cvt (RNE)
    return __builtin_bit_cast(unsigned short, b);
}

#define GLL(gsrc, ldst) \
    __builtin_amdgcn_global_load_lds((const __attribute__((address_space(1))) void*)(gsrc), \
                                     (__attribute__((address_space(3))) void*)(ldst), 16, 0, 0)

// ---------------------------------------------------------------------------
// Kernel 1: fp32 -> bf16 conversion / packing
// ---------------------------------------------------------------------------
__global__ __launch_bounds__(256) void k_convert(
    const float* __restrict__ z,  const float* __restrict__ wq,
    const float* __restrict__ wk, const float* __restrict__ wv,
    const float* __restrict__ wo,
    const float* __restrict__ bq, const float* __restrict__ bk,
    const float* __restrict__ bv,
    unsigned short* __restrict__ zb, unsigned short* __restrict__ wqkv,
    unsigned short* __restrict__ wob, float* __restrict__ biasf)
{
    int i = blockIdx.x * 256 + threadIdx.x;   // 0 .. 2097151
    {
        float4 v = ((const float4*)z)[i];
        ushort4 o; o.x = f2bf(v.x); o.y = f2bf(v.y); o.z = f2bf(v.z); o.w = f2bf(v.w);
        ((ushort4*)zb)[i] = o;
    }
    if (i < 262144) {   // 1048576/4 per weight matrix
        float4 v;
        ushort4 o;
        v = ((const float4*)wq)[i];
        o.x=f2bf(v.x); o.y=f2bf(v.y); o.z=f2bf(v.z); o.w=f2bf(v.w);
        ((ushort4*)wqkv)[i] = o;
        v = ((const float4*)wk)[i];
        o.x=f2bf(v.x); o.y=f2bf(v.y); o.z=f2bf(v.z); o.w=f2bf(v.w);
        ((ushort4*)wqkv)[262144 + i] = o;
        v = ((const float4*)wv)[i];
        o.x=f2bf(v.x); o.y=f2bf(v.y); o.z=f2bf(v.z); o.w=f2bf(v.w);
        ((ushort4*)wqkv)[524288 + i] = o;
        v = ((const float4*)wo)[i];
        o.x=f2bf(v.x); o.y=f2bf(v.y); o.z=f2bf(v.z); o.w=f2bf(v.w);
        ((ushort4*)wob)[i] = o;
    }
    if (i < 1024) {
        biasf[i]        = bq[i];
        biasf[1024 + i] = bk[i];
        biasf[2048 + i] = bv[i];
    }
}

// ---------------------------------------------------------------------------
// Kernel 2: QKV projection GEMM  C[8192,3072] = zb * wqkv^T + bias
// ---------------------------------------------------------------------------
__global__ __launch_bounds__(256) void k_gemm_qkv(
    const unsigned short* __restrict__ A,   // [8192][1024] bf16
    const unsigned short* __restrict__ Bw,  // [3072][1024] bf16
    const float* __restrict__ biasf,        // [3072]
    unsigned short* __restrict__ qb, unsigned short* __restrict__ kb,
    unsigned short* __restrict__ vtb)
{
    __shared__ unsigned short lds_a[128 * 32];
    __shared__ unsigned short lds_b[128 * 32];

    const int NT = 3072 / 128;  // 24
    int bid = blockIdx.x;
    int tn = bid % NT, tm = bid / NT;
    int m0 = tm * 128, n0 = tn * 128;
    int tid = threadIdx.x, wid = tid >> 6, lane = tid & 63;
    int wm = wid >> 1, wn = wid & 1;

    f32x4 acc[4][4] = {};

    int srow = lane >> 2;        // 0..15
    int scol = (lane & 3) * 8;   // element offset within 32-col row

    for (int kt = 0; kt < 32; ++kt) {
        int k0 = kt * 32;
#pragma unroll
        for (int i = 0; i < 2; ++i) {
            int rb = (wid * 2 + i) * 16;
            GLL(A  + (size_t)(m0 + rb + srow) * 1024 + k0 + scol, lds_a + rb * 32);
            GLL(Bw + (size_t)(n0 + rb + srow) * 1024 + k0 + scol, lds_b + rb * 32);
        }
        __syncthreads();
        bf16x8 af[4], bfr[4];
#pragma unroll
        for (int i = 0; i < 4; ++i)
            af[i] = *(const bf16x8*)(lds_a + (wm * 64 + i * 16 + (lane & 15)) * 32 + (lane >> 4) * 8);
#pragma unroll
        for (int j = 0; j < 4; ++j)
            bfr[j] = *(const bf16x8*)(lds_b + (wn * 64 + j * 16 + (lane & 15)) * 32 + (lane >> 4) * 8);
#pragma unroll
        for (int i = 0; i < 4; ++i)
#pragma unroll
            for (int j = 0; j < 4; ++j)
                acc[i][j] = __builtin_amdgcn_mfma_f32_16x16x32_bf16(af[i], bfr[j], acc[i][j], 0, 0, 0);
        __syncthreads();
    }

    int t = n0 >> 10;  // 0=Q 1=K 2=V
#pragma unroll
    for (int j = 0; j < 4; ++j) {
        int col = n0 + wn * 64 + j * 16 + (lane & 15);
        float bias = biasf[col];
        int d  = col & 1023;
        int h  = d >> 6;
        int dk = d & 63;
#pragma unroll
        for (int i = 0; i < 4; ++i) {
#pragma unroll
            for (int r = 0; r < 4; ++r) {
                int row = m0 + wm * 64 + i * 16 + (lane >> 4) * 4 + r;
                float v = acc[i][j][r] + bias;
                unsigned short bv16 = f2bf(v);
                int b_ = row >> 11, s_ = row & 2047;
                int bh = b_ * NHEAD + h;
                if (t == 0)      qb[((size_t)bh * SEQ + s_) * DKH + dk] = bv16;
                else if (t == 1) kb[((size_t)bh * SEQ + s_) * DKH + dk] = bv16;
                else             vtb[((size_t)bh * DKH + dk) * SEQ + s_] = bv16;
            }
        }
    }
}

// ---------------------------------------------------------------------------
// Kernel 3: flash attention, swapped-operand structure.
//   1 block = one (b,h) x 128 q-rows; 4 waves x 32 q-rows (2 sub-blocks of 16).
//   S^T = mfma(K, Q): columns = q -> softmax reduce = 15 local + 2 shfl ops,
//   and S^T's C-layout (row = 4g+r) IS the B-frag layout (k = 4g+e) of
//   mfma_f32_16x16x16_bf16 -> P feeds PV directly from registers (no LDS).
//   O^T = mfma(V^T, P): columns = q -> alpha rescale / 1/l lane-local.
//   K/V double-buffered via global_load_lds + counted vmcnt(4) (T3-lite).
// ---------------------------------------------------------------------------
__device__ __forceinline__ void stage_kv(
    const unsigned short* __restrict__ kb, const unsigned short* __restrict__ vtb,
    unsigned short* lk, unsigned short* lv,
    int bh, int t, int wid, int srow8, int sc)
{
#pragma unroll
    for (int i = 0; i < 2; ++i) {
        int rb = wid * 16 + i * 8;
        int row = rb + srow8;
        int cs = (sc ^ (row & 7)) * 8;   // inverse-swizzled global source chunk
        GLL(kb  + ((size_t)bh * SEQ + t * 64 + row) * DKH + cs, lk + rb * 64);
        GLL(vtb + ((size_t)bh * DKH + row) * SEQ + t * 64 + cs, lv + rb * 64);
    }
}

__global__ __launch_bounds__(256) void k_attn(
    const unsigned short* __restrict__ qg,
    const unsigned short* __restrict__ kb,
    const unsigned short* __restrict__ vtb,
    unsigned short* __restrict__ ctxb)
{
    __shared__ unsigned short lds_k[2][64 * 64];
    __shared__ unsigned short lds_v[2][64 * 64];

    int bid = blockIdx.x;
    // XCD-grouped swizzle: all 16 q-tiles of a (b,h) land on the same XCD.
    int x = bid & 7, li = bid >> 3;
    int bh = x * 8 + (li >> 4);
    int qt = li & 15;

    int tid = threadIdx.x, wid = tid >> 6, lane = tid & 63;
    int lq = lane & 15, g = lane >> 4;
    int srow8 = lane >> 3, sc = lane & 7;

    // Q fragments: 2 q-sub-blocks x 2 k-halves, kept in registers
    bf16x8 aq[2][2];
    {
        const unsigned short* qp = qg + ((size_t)bh * SEQ + qt * 128 + wid * 32 + lq) * DKH + g * 8;
        aq[0][0] = *(const bf16x8*)(qp);
        aq[0][1] = *(const bf16x8*)(qp + 32);
        aq[1][0] = *(const bf16x8*)(qp + 16 * DKH);
        aq[1][1] = *(const bf16x8*)(qp + 16 * DKH + 32);
    }

    float m2[2]   = { -1e30f, -1e30f };
    float lsum[2] = { 0.f, 0.f };
    f32x4 oacc[2][4] = {};

    const float SC = 0.125f;      // 1/sqrt(64)
    const float THR = 8.0f;       // defer-max threshold (T13)

    stage_kv(kb, vtb, &lds_k[0][0], &lds_v[0][0], bh, 0, wid, srow8, sc);

    for (int kt = 0; kt < 32; ++kt) {
        int cur = kt & 1;
        if (kt < 31) {
            stage_kv(kb, vtb, &lds_k[cur ^ 1][0], &lds_v[cur ^ 1][0], bh, kt + 1, wid, srow8, sc);
            asm volatile("s_waitcnt vmcnt(4)" ::: "memory");
        } else {
            asm volatile("s_waitcnt vmcnt(0)" ::: "memory");
        }
        __builtin_amdgcn_s_barrier();

        // ---- S^T = K Q^T : st[q][jb] cols = q-row (lane&15), rows = kv 4g+r ----
        f32x4 st[2][4] = {};
#pragma unroll
        for (int kk = 0; kk < 2; ++kk) {
            bf16x8 kf[4];
#pragma unroll
            for (int jb = 0; jb < 4; ++jb) {
                int row = jb * 16 + lq;
                int c = kk * 4 + g;
                kf[jb] = *(const bf16x8*)(&lds_k[cur][row * 64 + ((c ^ (row & 7)) * 8)]);
            }
#pragma unroll
            for (int jb = 0; jb < 4; ++jb)
#pragma unroll
                for (int q = 0; q < 2; ++q)
                    st[q][jb] = __builtin_amdgcn_mfma_f32_16x16x32_bf16(kf[jb], aq[q][kk], st[q][jb], 0, 0, 0);
        }

        // ---- online softmax (columns are lane-local) ----
        float mt[2];
        bool need = false;
#pragma unroll
        for (int q = 0; q < 2; ++q) {
            float a0 = fmaxf(fmaxf(st[q][0][0], st[q][0][1]), fmaxf(st[q][0][2], st[q][0][3]));
            float a1 = fmaxf(fmaxf(st[q][1][0], st[q][1][1]), fmaxf(st[q][1][2], st[q][1][3]));
            float a2 = fmaxf(fmaxf(st[q][2][0], st[q][2][1]), fmaxf(st[q][2][2], st[q][2][3]));
            float a3 = fmaxf(fmaxf(st[q][3][0], st[q][3][1]), fmaxf(st[q][3][2], st[q][3][3]));
            float t0 = fmaxf(fmaxf(a0, a1), fmaxf(a2, a3));
            t0 = fmaxf(t0, __shfl_xor(t0, 16));
            t0 = fmaxf(t0, __shfl_xor(t0, 32));
            mt[q] = t0 * SC;
            need = need || (mt[q] > m2[q] + THR);
        }
        if (__any(need)) {
#pragma unroll
            for (int q = 0; q < 2; ++q) {
                float mn = fmaxf(m2[q], mt[q]);
                float alpha = __expf(m2[q] - mn);
                m2[q] = mn;
                lsum[q] *= alpha;
#pragma unroll
                for (int dj = 0; dj < 4; ++dj) {
                    oacc[q][dj][0] *= alpha; oacc[q][dj][1] *= alpha;
                    oacc[q][dj][2] *= alpha; oacc[q][dj][3] *= alpha;
                }
            }
        }

        short4v w[2][4];
#pragma unroll
        for (int q = 0; q < 2; ++q) {
            float s = 0.f;
#pragma unroll
            for (int jb = 0; jb < 4; ++jb) {
                float p0 = __expf(st[q][jb][0] * SC - m2[q]);
                float p1 = __expf(st[q][jb][1] * SC - m2[q]);
                float p2 = __expf(st[q][jb][2] * SC - m2[q]);
                float p3 = __expf(st[q][jb][3] * SC - m2[q]);
                s += (p0 + p1) + (p2 + p3);
                bf16x4v pb;
                pb[0] = (__bf16)p0; pb[1] = (__bf16)p1; pb[2] = (__bf16)p2; pb[3] = (__bf16)p3;
                w[q][jb] = __builtin_bit_cast(short4v, pb);
            }
            s += __shfl_xor(s, 16);
            s += __shfl_xor(s, 32);
            lsum[q] += s;
        }

        // ---- O^T += V^T @ P  (16x16x16, B-frag = S^T C-layout, no exchange) ----
#pragma unroll
        for (int dj = 0; dj < 4; ++dj) {
            int row = dj * 16 + lq;
            int rx = row & 7;
#pragma unroll
            for (int jb = 0; jb < 4; ++jb) {
                int c = jb * 2 + (g >> 1);
                short4v vf = *(const short4v*)(&lds_v[cur][row * 64 + ((c ^ rx) * 8) + (g & 1) * 4]);
#pragma unroll
                for (int q = 0; q < 2; ++q)
                    oacc[q][dj] = __builtin_amdgcn_mfma_f32_16x16x16bf16_1k(vf, w[q][jb], oacc[q][dj], 0, 0, 0);
            }
        }
        __builtin_amdgcn_s_barrier();
    }

    // ---- epilogue: ctx[b,s,h,dk] bf16, paired u32 stores ----
    int b_ = bh >> 4, h = bh & 15;
#pragma unroll
    for (int q = 0; q < 2; ++q) {
        float inv = 1.0f / lsum[q];
        int s_ = qt * 128 + wid * 32 + q * 16 + lq;
        unsigned short* op = ctxb + (((size_t)b_ * SEQ + s_) * NHEAD + h) * DKH;
#pragma unroll
        for (int dj = 0; dj < 4; ++dj) {
#pragma unroll
            for (int t = 0; t < 2; ++t) {
                unsigned short e0 = f2bf(oacc[q][dj][2 * t]     * inv);
                unsigned short e1 = f2bf(oacc[q][dj][2 * t + 1] * inv);
                unsigned int u = ((unsigned int)e1 << 16) | (unsigned int)e0;
                *(unsigned int*)(op + dj * 16 + 4 * g + 2 * t) = u;
            }
        }
    }
}

// ---------------------------------------------------------------------------
// Kernel 4: output projection  out[8192,1024] = ctxb * wob^T + bo  (fp32 out)
// ---------------------------------------------------------------------------
__global__ __launch_bounds__(256) void k_gemm_out(
    const unsigned short* __restrict__ A,    // ctxb [8192][1024] bf16
    const unsigned short* __restrict__ Bw,   // wob  [1024][1024] bf16
    const float* __restrict__ bo,
    float* __restrict__ out)
{
    __shared__ unsigned short lds_a[128 * 32];
    __shared__ unsigned short lds_b[128 * 32];

    const int NT = 1024 / 128;  // 8
    int bid = blockIdx.x;
    int tn = bid % NT, tm = bid / NT;
    int m0 = tm * 128, n0 = tn * 128;
    int tid = threadIdx.x, wid = tid >> 6, lane = tid & 63;
    int wm = wid >> 1, wn = wid & 1;

    f32x4 acc[4][4] = {};

    int srow = lane >> 2;
    int scol = (lane & 3) * 8;

    for (int kt = 0; kt < 32; ++kt) {
        int k0 = kt * 32;
#pragma unroll
        for (int i = 0; i < 2; ++i) {
            int rb = (wid * 2 + i) * 16;
            GLL(A  + (size_t)(m0 + rb + srow) * 1024 + k0 + scol, lds_a + rb * 32);
            GLL(Bw + (size_t)(n0 + rb + srow) * 1024 + k0 + scol, lds_b + rb * 32);
        }
        __syncthreads();
        bf16x8 af[4], bfr[4];
#pragma unroll
        for (int i = 0; i < 4; ++i)
            af[i] = *(const bf16x8*)(lds_a + (wm * 64 + i * 16 + (lane & 15)) * 32 + (lane >> 4) * 8);
#pragma unroll
        for (int j = 0; j < 4; ++j)
            bfr[j] = *(const bf16x8*)(lds_b + (wn * 64 + j * 16 + (lane & 15)) * 32 + (lane >> 4) * 8);
#pragma unroll
        for (int i = 0; i < 4; ++i)
#pragma unroll
            for (int j = 0; j < 4; ++j)
                acc[i][j] = __builtin_amdgcn_mfma_f32_16x16x32_bf16(af[i], bfr[j], acc[i][j], 0, 0, 0);
        __syncthreads();
    }

#pragma unroll
    for (int j = 0; j < 4; ++j) {
        int col = n0 + wn * 64 + j * 16 + (lane & 15);
        float bias = bo[col];
#pragma unroll
        for (int i = 0; i < 4; ++i) {
#pragma unroll
            for (int r = 0; r < 4; ++r) {
                int row = m0 + wm * 64 + i * 16 + (lane >> 4) * 4 + r;
                out[(size_t)row * 1024 + col] = acc[i][j][r] + bias;
            }
        }
    }
}

// ---------------------------------------------------------------------------
extern "C" void kernel_launch(void* const* d_in, const int* in_sizes, int n_in,
                              void* d_out, int out_size, void* d_ws, size_t ws_size,
                              hipStream_t stream)
{
    const float* z  = (const float*)d_in[0];
    const float* Wq = (const float*)d_in[1];
    const float* bq = (const float*)d_in[2];
    const float* Wk = (const float*)d_in[3];
    const float* bk = (const float*)d_in[4];
    const float* Wv = (const float*)d_in[5];
    const float* bv = (const float*)d_in[6];
    const float* Wo = (const float*)d_in[7];
    const float* bo = (const float*)d_in[8];
    float* out = (float*)d_out;

    char* ws = (char*)d_ws;
    unsigned short* zb   = (unsigned short*)(ws);                        // 16 MB
    unsigned short* ctxb = (unsigned short*)(ws);                        // 16 MB (reuse)
    unsigned short* wqkv = (unsigned short*)(ws + (16ull << 20));        //  6 MB
    unsigned short* wob  = (unsigned short*)(ws + (22ull << 20));        //  2 MB
    float*          biasf= (float*)(ws + (24ull << 20));                 // 12 KB
    unsigned short* qb   = (unsigned short*)(ws + (25ull << 20));        // 16 MB
    unsigned short* kb   = (unsigned short*)(ws + (41ull << 20));        // 16 MB
    unsigned short* vtb  = (unsigned short*)(ws + (57ull << 20));        // 16 MB -> 73 MB total

    k_convert<<<8192, 256, 0, stream>>>(z, Wq, Wk, Wv, Wo, bq, bk, bv, zb, wqkv, wob, biasf);
    k_gemm_qkv<<<64 * 24, 256, 0, stream>>>(zb, wqkv, biasf, qb, kb, vtb);
    k_attn<<<NBH * 16, 256, 0, stream>>>(qb, kb, vtb, ctxb);
    k_gemm_out<<<64 * 8, 256, 0, stream>>>(ctxb, wob, bo, out);
}